// Round 8
// baseline (191.608 us; speedup 1.0000x reference)
//
#include <hip/hip_runtime.h>
#include <hip/hip_fp16.h>

// PQ sim: sim = decode(x) @ decode(tgt)^T via f16 GEMM (K=512).
// R8: persistent-block GEMM. 512 blocks (2/CU) x 8 tiles of 128x128.
// Ring-of-4 LDS (64 KB), continuous staging across tile boundaries,
// epilogue stores of tile T interleaved 4/step into tile T+1's K-loop
// (double acc set). Uniform step: [4 st][4 ld][16 MFMA][vmcnt(8)][bar].
// Per-XCD bn-stripe (B-panel L2-resident), 2-way LDS chunk swizzle.

#define D_FULL 512
#define M_SUB 64
#define KSUB 256
#define DSUB 8
#define KP 512

typedef _Float16 f16x8 __attribute__((ext_vector_type(8)));
typedef float f32x4 __attribute__((ext_vector_type(4)));

static __device__ __forceinline__ unsigned int pack2h(float f0, float f1) {
  _Float16 h0 = (_Float16)f0, h1 = (_Float16)f1;
  unsigned short u0, u1;
  __builtin_memcpy(&u0, &h0, 2);
  __builtin_memcpy(&u1, &h1, 2);
  return (unsigned int)u0 | ((unsigned int)u1 << 16);
}

// ---------------- encode + decode queries into A' (f16) ----------------
__global__ void encode_kernel(const float* __restrict__ x,
                              const float* __restrict__ cen,
                              unsigned short* __restrict__ Ap) {
  __shared__ float cs[KSUB][DSUB];
  __shared__ float n2[KSUB];
  const int t = threadIdx.x;
  const int s = blockIdx.x;
  const int i = blockIdx.y * 256 + t;

  const float* cp = cen + ((size_t)s * KSUB + t) * DSUB;
  float4 c0 = *(const float4*)cp;
  float4 c1 = *(const float4*)(cp + 4);
  *(float4*)&cs[t][0] = c0;
  *(float4*)&cs[t][4] = c1;
  n2[t] = c0.x * c0.x + c0.y * c0.y + c0.z * c0.z + c0.w * c0.w +
          c1.x * c1.x + c1.y * c1.y + c1.z * c1.z + c1.w * c1.w;
  __syncthreads();

  float xq[8];
  const float* xp = x + (size_t)i * D_FULL + s * DSUB;
  *(float4*)&xq[0] = *(const float4*)xp;
  *(float4*)&xq[4] = *(const float4*)(xp + 4);

  float best = 1e30f;
  int bk = 0;
  for (int k = 0; k < KSUB; ++k) {
    float dot = 0.f;
#pragma unroll
    for (int d = 0; d < 8; ++d) dot += cs[k][d] * xq[d];
    float dis = n2[k] - 2.0f * dot;
    if (dis < best) { best = dis; bk = k; }  // strict < = numpy argmin tie rule
  }

  uint4 hv;
  hv.x = pack2h(cs[bk][0], cs[bk][1]);
  hv.y = pack2h(cs[bk][2], cs[bk][3]);
  hv.z = pack2h(cs[bk][4], cs[bk][5]);
  hv.w = pack2h(cs[bk][6], cs[bk][7]);
  *(uint4*)(Ap + (size_t)i * KP + s * DSUB) = hv;
}

// ---------------- decode targets into B' (f16) ----------------
__global__ void decode_tgt(const int* __restrict__ tgt,
                           const float* __restrict__ cen,
                           unsigned short* __restrict__ Bp) {
  int g = blockIdx.x * 256 + threadIdx.x;
  int j = g >> 6, s = g & 63;
  int k = tgt[g];
  const float* c = cen + ((size_t)s * KSUB + k) * DSUB;
  float4 v0 = *(const float4*)c;
  float4 v1 = *(const float4*)(c + 4);
  uint4 hv;
  hv.x = pack2h(v0.x, v0.y);
  hv.y = pack2h(v0.z, v0.w);
  hv.z = pack2h(v1.x, v1.y);
  hv.w = pack2h(v1.z, v1.w);
  *(uint4*)(Bp + (size_t)j * KP + s * DSUB) = hv;
}

// ---------------- persistent GEMM ----------------
// Slot (16 KB): A 128x32 f16 + B 128x32 f16. Row = 64 B = 4 chunks of 16 B.
// Phys chunk p at row r holds logical chunk p ^ ((r>>1)&3): 2-way banks (free).
// Stage: linear LDS dest (wave-uniform + lane*16) + inverse-swizzled source.

#define GLL(SRC, DST)                                                          \
  __builtin_amdgcn_global_load_lds(                                            \
      (const __attribute__((address_space(1))) void*)(SRC),                    \
      (__attribute__((address_space(3))) void*)(DST), 16, 0, 0)

#define STG(ABASE, K0, SLOT)                                                   \
  {                                                                            \
    const unsigned short* a0_ = (ABASE) + aoff + (K0);                         \
    const unsigned short* b0_ = Bb + aoff + (K0);                              \
    unsigned short* d_ = lds + (SLOT)*8192 + tid * 8;                          \
    GLL(a0_, d_);                                                              \
    GLL(a0_ + (size_t)64 * KP, d_ + 2048);                                     \
    GLL(b0_, d_ + 4096);                                                       \
    GLL(b0_ + (size_t)64 * KP, d_ + 6144);                                     \
  }

#define COMP(SLOT, AC)                                                         \
  {                                                                            \
    const unsigned short* as_ = lds + (SLOT)*8192;                             \
    const unsigned short* bs_ = as_ + 4096;                                    \
    f16x8 a_[4], b_[4];                                                        \
    _Pragma("unroll") for (int i2 = 0; i2 < 4; ++i2) {                         \
      int row = wm * 64 + i2 * 16 + l16;                                       \
      a_[i2] = *(const f16x8*)&as_[row * 32 + ((kq ^ ((row >> 1) & 3)) * 8)];  \
    }                                                                          \
    _Pragma("unroll") for (int j2 = 0; j2 < 4; ++j2) {                         \
      int row = wn * 64 + j2 * 16 + l16;                                       \
      b_[j2] = *(const f16x8*)&bs_[row * 32 + ((kq ^ ((row >> 1) & 3)) * 8)];  \
    }                                                                          \
    __builtin_amdgcn_s_setprio(1);                                             \
    _Pragma("unroll") for (int i2 = 0; i2 < 4; ++i2)                           \
        _Pragma("unroll") for (int j2 = 0; j2 < 4; ++j2) AC[i2][j2] =          \
        __builtin_amdgcn_mfma_f32_16x16x32_f16(a_[i2], b_[j2], AC[i2][j2], 0,  \
                                               0, 0);                          \
    __builtin_amdgcn_s_setprio(0);                                             \
  }

#define VMW_(N) asm volatile("s_waitcnt vmcnt(" #N ")" ::: "memory")
#define VMW(N) VMW_(N)
#define BAR() __builtin_amdgcn_s_barrier()

// Store chunk s (4 scalars) of SET to CP (s literal -> static reg indexing).
#define STREAL(SET, s, CP)                                                     \
  {                                                                            \
    _Pragma("unroll") for (int r = 0; r < 4; ++r)(CP)[                         \
        (size_t)(((s) >> 2) * 16 + r) * Nt + ((s)&3) * 16] =                   \
        SET[(s) >> 2][(s)&3][r];                                               \
  }
#define STNONE(SET, s, CP)

#define ZERO(AC)                                                               \
  {                                                                            \
    _Pragma("unroll") for (int i = 0; i < 4; ++i)                              \
        _Pragma("unroll") for (int j = 0; j < 4; ++j) AC[i][j] =               \
        (f32x4){0.f, 0.f, 0.f, 0.f};                                           \
  }

// One tile: 16 steps. Step s: [stores chunk s of AS][stage k-slice s+2]
// [compute slice s from slot s&3][vmcnt][barrier]. Steps 14,15 stage the
// NEXT tile's slices 0,1 (pipeline never drains). VMN=8 with stores, 4 без.
#define TBODY(AC, AS, ABC, ABN, STX, CP, VMN)                                  \
  ZERO(AC);                                                                    \
  STX(AS, 0, CP) STG(ABC, 64, 2) COMP(0, AC) VMW(VMN); BAR();                  \
  STX(AS, 1, CP) STG(ABC, 96, 3) COMP(1, AC) VMW(VMN); BAR();                  \
  STX(AS, 2, CP) STG(ABC, 128, 0) COMP(2, AC) VMW(VMN); BAR();                 \
  STX(AS, 3, CP) STG(ABC, 160, 1) COMP(3, AC) VMW(VMN); BAR();                 \
  STX(AS, 4, CP) STG(ABC, 192, 2) COMP(0, AC) VMW(VMN); BAR();                 \
  STX(AS, 5, CP) STG(ABC, 224, 3) COMP(1, AC) VMW(VMN); BAR();                 \
  STX(AS, 6, CP) STG(ABC, 256, 0) COMP(2, AC) VMW(VMN); BAR();                 \
  STX(AS, 7, CP) STG(ABC, 288, 1) COMP(3, AC) VMW(VMN); BAR();                 \
  STX(AS, 8, CP) STG(ABC, 320, 2) COMP(0, AC) VMW(VMN); BAR();                 \
  STX(AS, 9, CP) STG(ABC, 352, 3) COMP(1, AC) VMW(VMN); BAR();                 \
  STX(AS, 10, CP) STG(ABC, 384, 0) COMP(2, AC) VMW(VMN); BAR();                \
  STX(AS, 11, CP) STG(ABC, 416, 1) COMP(3, AC) VMW(VMN); BAR();                \
  STX(AS, 12, CP) STG(ABC, 448, 2) COMP(0, AC) VMW(VMN); BAR();                \
  STX(AS, 13, CP) STG(ABC, 480, 3) COMP(1, AC) VMW(VMN); BAR();                \
  STX(AS, 14, CP) STG(ABN, 0, 0) COMP(2, AC) VMW(VMN); BAR();                  \
  STX(AS, 15, CP) STG(ABN, 32, 1) COMP(3, AC) VMW(VMN); BAR();

__global__ __launch_bounds__(256, 2) void gemm_nt(
    const unsigned short* __restrict__ A, const unsigned short* __restrict__ B,
    float* __restrict__ C, int Nt) {
  __shared__ unsigned short lds[4 * 8192];  // 64 KB ring-of-4
  const int tid = threadIdx.x;
  const int w = tid >> 6, l = tid & 63;
  const int wm = w >> 1, wn = w & 1;
  const int l16 = l & 15, kq = l >> 4;

  // Persistent mapping: XCD x owns bn-stripe [x*16, x*16+16) (2 MB B,
  // L2-resident all kernel). Block: fixed bn, bm walks bm0+4t (t=0..7);
  // concurrent blocks per XCD share a 4-row A panel phase (512 KB).
  const int bid = blockIdx.x;
  const int xcd = bid & 7;
  const int j = bid >> 3;                // 0..63
  const int bn = xcd * 16 + (j & 15);    // 0..127
  const int bm0 = j >> 4;                // 0..3

  const unsigned short* Bb = B + (size_t)bn * 128 * KP;
  const size_t TS = (size_t)512 * KP;  // A advance per tile (4 bm x 128 rows)
#define ABT(T) (A + ((size_t)(bm0 + 4 * (T)) * 128) * KP)

  // Per-thread stage offset: row tid>>2, phys chunk tid&3 holds logical
  // chunk (tid&3)^((row>>1)&3) -> inverse-swizzled global source.
  const int Ra = tid >> 2;
  const size_t aoff =
      (size_t)Ra * KP + (size_t)(((tid & 3) ^ ((Ra >> 1) & 3)) * 8);

  // C store base for tile 0; advance 512 rows per tile.
  float* Cp = C + ((size_t)(bm0 * 128) + wm * 64 + (l >> 4) * 4) * Nt +
              bn * 128 + wn * 64 + l16;
  const size_t CADV = (size_t)512 * Nt;

  f32x4 accE[4][4], accO[4][4];

  // Prologue: slices 0,1 of tile 0; drain oldest 4 -> slot 0 ready.
  STG(ABT(0), 0, 0);
  STG(ABT(0), 32, 1);
  VMW(4);
  BAR();

  // T0: compute accE, no stores (vmcnt(4): only next slice in flight).
  TBODY(accE, accO, ABT(0), ABT(1), STNONE, Cp, 4)
  // T1: compute accO, store tile0 (accE); uniform vmcnt(8) from here.
  TBODY(accO, accE, ABT(1), ABT(2), STREAL, Cp, 8)

  // T = 2,3 / 4,5 / 6,7 (acc ping-pong, static reg indexing).
  const unsigned short* abc = ABT(2);
  float* cp1 = Cp + CADV;
  for (int it = 0; it < 3; ++it) {
    const unsigned short* abn2 = (it == 2) ? ABT(0) : abc + 2 * TS;  // wrap
    TBODY(accE, accO, abc, abc + TS, STREAL, cp1, 8)
    TBODY(accO, accE, abc + TS, abn2, STREAL, cp1 + CADV, 8)
    abc += 2 * TS;
    cp1 += 2 * CADV;
  }

  // Final: tile 7's acc (accO) stored un-interleaved (~1/8 of writes).
  float* cpF = Cp + (size_t)7 * CADV;
#pragma unroll
  for (int i2 = 0; i2 < 4; ++i2)
#pragma unroll
    for (int j2 = 0; j2 < 4; ++j2)
#pragma unroll
      for (int r = 0; r < 4; ++r)
        cpF[(size_t)(i2 * 16 + r) * Nt + j2 * 16] = accO[i2][j2][r];
}

extern "C" void kernel_launch(void* const* d_in, const int* in_sizes, int n_in,
                              void* d_out, int out_size, void* d_ws, size_t ws_size,
                              hipStream_t stream) {
  const float* x = (const float*)d_in[0];    // [n, 512]
  const float* cen = (const float*)d_in[1];  // [64, 256, 8]
  const int* tgt = (const int*)d_in[2];      // [m, 64]
  float* out = (float*)d_out;                // [n, m]
  const int n = in_sizes[0] / D_FULL;        // 4096
  const int m = in_sizes[2] / M_SUB;         // 16384

  unsigned short* Ap = (unsigned short*)d_ws;  // [n, 512] f16
  unsigned short* Bp = Ap + (size_t)n * KP;    // [m, 512] f16

  encode_kernel<<<dim3(M_SUB, n / 256), 256, 0, stream>>>(x, cen, Ap);
  decode_tgt<<<dim3((m * M_SUB) / 256), 256, 0, stream>>>(tgt, cen, Bp);
  gemm_nt<<<dim3(512), 256, 0, stream>>>(Ap, Bp, out, m);
}

// Round 9
// 134.209 us; speedup vs baseline: 1.4277x; 1.4277x over previous
//
#include <hip/hip_runtime.h>
#include <hip/hip_fp16.h>

// PQ sim: sim = decode(x) @ decode(tgt)^T via f16 GEMM (K=512).
// R9: encode restructured Q=4 (each thread: 4 queries per codebook broadcast,
// 4x fewer LDS ops — encode was LDS-issue-bound ~40us). GEMM/decode = R6 base:
// BM=256 BN=128 BK=64, 8 waves, ring-of-3 (144 KB), vmcnt(6), XOR swizzle,
// setprio, XCD-pinned supertile mapping.

#define D_FULL 512
#define M_SUB 64
#define KSUB 256
#define DSUB 8
#define KP 512

typedef _Float16 f16x8 __attribute__((ext_vector_type(8)));
typedef float f32x4 __attribute__((ext_vector_type(4)));

static __device__ __forceinline__ unsigned int pack2h(float f0, float f1) {
  _Float16 h0 = (_Float16)f0, h1 = (_Float16)f1;
  unsigned short u0, u1;
  __builtin_memcpy(&u0, &h0, 2);
  __builtin_memcpy(&u1, &h1, 2);
  return (unsigned int)u0 | ((unsigned int)u1 << 16);
}

// ---------------- encode + decode queries into A' (f16) ----------------
// grid (64, n/1024), block 256. Thread t: queries by*1024 + t + {0,256,512,768}
// (all same subspace s). Codebook rows broadcast-read once per 4 queries.
__global__ void encode_kernel(const float* __restrict__ x,
                              const float* __restrict__ cen,
                              unsigned short* __restrict__ Ap) {
  __shared__ float cs[KSUB][DSUB];
  __shared__ float n2[KSUB];
  const int t = threadIdx.x;
  const int s = blockIdx.x;
  const int i0 = blockIdx.y * 1024 + t;

  const float* cp = cen + ((size_t)s * KSUB + t) * DSUB;
  float4 c0 = *(const float4*)cp;
  float4 c1 = *(const float4*)(cp + 4);
  *(float4*)&cs[t][0] = c0;
  *(float4*)&cs[t][4] = c1;
  n2[t] = c0.x * c0.x + c0.y * c0.y + c0.z * c0.z + c0.w * c0.w +
          c1.x * c1.x + c1.y * c1.y + c1.z * c1.z + c1.w * c1.w;
  __syncthreads();

  float xq[4][8];
#pragma unroll
  for (int q = 0; q < 4; ++q) {
    const float* xp = x + (size_t)(i0 + q * 256) * D_FULL + s * DSUB;
    *(float4*)&xq[q][0] = *(const float4*)xp;
    *(float4*)&xq[q][4] = *(const float4*)(xp + 4);
  }

  float best[4] = {1e30f, 1e30f, 1e30f, 1e30f};
  int bk[4] = {0, 0, 0, 0};
#pragma unroll 4
  for (int k = 0; k < KSUB; ++k) {
    float c[8];
    *(float4*)&c[0] = *(const float4*)&cs[k][0];
    *(float4*)&c[4] = *(const float4*)&cs[k][4];
    const float nn = n2[k];
#pragma unroll
    for (int q = 0; q < 4; ++q) {
      float dot = 0.f;
#pragma unroll
      for (int d = 0; d < 8; ++d) dot += c[d] * xq[q][d];
      float dis = nn - 2.0f * dot;
      if (dis < best[q]) { best[q] = dis; bk[q] = k; }  // strict < = numpy tie
    }
  }

#pragma unroll
  for (int q = 0; q < 4; ++q) {
    const int b = bk[q];
    uint4 hv;
    hv.x = pack2h(cs[b][0], cs[b][1]);
    hv.y = pack2h(cs[b][2], cs[b][3]);
    hv.z = pack2h(cs[b][4], cs[b][5]);
    hv.w = pack2h(cs[b][6], cs[b][7]);
    *(uint4*)(Ap + (size_t)(i0 + q * 256) * KP + s * DSUB) = hv;
  }
}

// ---------------- decode targets into B' (f16) ----------------
__global__ void decode_tgt(const int* __restrict__ tgt,
                           const float* __restrict__ cen,
                           unsigned short* __restrict__ Bp) {
  int g = blockIdx.x * 256 + threadIdx.x;
  int j = g >> 6, s = g & 63;
  int k = tgt[g];
  const float* c = cen + ((size_t)s * KSUB + k) * DSUB;
  float4 v0 = *(const float4*)c;
  float4 v1 = *(const float4*)(c + 4);
  uint4 hv;
  hv.x = pack2h(v0.x, v0.y);
  hv.y = pack2h(v0.z, v0.w);
  hv.z = pack2h(v1.x, v1.y);
  hv.w = pack2h(v1.z, v1.w);
  *(uint4*)(Bp + (size_t)j * KP + s * DSUB) = hv;
}

// ---------------- GEMM: C[n,m] = A'[n,KP] * B'[m,KP]^T (R6, unchanged) ----
#define STAGE(T, SLOT)                                                          \
  do {                                                                          \
    const int k0_ = (T) * 64;                                                   \
    unsigned short* as_ = &lds[(SLOT) * 24576];                                 \
    unsigned short* bs_ = as_ + 16384;                                          \
    _Pragma("unroll") for (int it = 0; it < 4; ++it) {                          \
      int R = w * 32 + it * 8;                                                  \
      int r = R + (l >> 3);                                                     \
      int c = (l & 7) ^ (r & 7);                                                \
      __builtin_amdgcn_global_load_lds(                                         \
          (const __attribute__((address_space(1))) void*)(Ab + (size_t)r * KP + \
                                                          k0_ + c * 8),         \
          (__attribute__((address_space(3))) void*)(as_ + R * 64 + l * 8), 16,  \
          0, 0);                                                                \
    }                                                                           \
    _Pragma("unroll") for (int it = 0; it < 2; ++it) {                          \
      int R = w * 16 + it * 8;                                                  \
      int r = R + (l >> 3);                                                     \
      int c = (l & 7) ^ (r & 7);                                                \
      __builtin_amdgcn_global_load_lds(                                         \
          (const __attribute__((address_space(1))) void*)(Bb + (size_t)r * KP + \
                                                          k0_ + c * 8),         \
          (__attribute__((address_space(3))) void*)(bs_ + R * 64 + l * 8), 16,  \
          0, 0);                                                                \
    }                                                                           \
  } while (0)

#define COMPUTE(SLOT)                                                           \
  do {                                                                          \
    const unsigned short* as_ = &lds[(SLOT) * 24576];                           \
    const unsigned short* bs_ = as_ + 16384;                                    \
    _Pragma("unroll") for (int ks = 0; ks < 2; ++ks) {                          \
      f16x8 a_[4], b_[4];                                                       \
      int kq = ks * 4 + (l >> 4);                                               \
      _Pragma("unroll") for (int i2 = 0; i2 < 4; ++i2) {                        \
        int row = wm * 64 + i2 * 16 + (l & 15);                                 \
        a_[i2] = *(const f16x8*)&as_[row * 64 + ((kq ^ (row & 7)) * 8)];        \
      }                                                                         \
      _Pragma("unroll") for (int j2 = 0; j2 < 4; ++j2) {                        \
        int row = wn * 64 + j2 * 16 + (l & 15);                                 \
        b_[j2] = *(const f16x8*)&bs_[row * 64 + ((kq ^ (row & 7)) * 8)];        \
      }                                                                         \
      __builtin_amdgcn_s_setprio(1);                                            \
      _Pragma("unroll") for (int i2 = 0; i2 < 4; ++i2)                          \
          _Pragma("unroll") for (int j2 = 0; j2 < 4; ++j2) acc[i2][j2] =        \
          __builtin_amdgcn_mfma_f32_16x16x32_f16(a_[i2], b_[j2], acc[i2][j2],   \
                                                 0, 0, 0);                      \
      __builtin_amdgcn_s_setprio(0);                                            \
    }                                                                           \
  } while (0)

#define VMW(N) asm volatile("s_waitcnt vmcnt(" #N ")" ::: "memory")
#define BAR() __builtin_amdgcn_s_barrier()

__global__ __launch_bounds__(512, 2) void gemm_nt(
    const unsigned short* __restrict__ A, const unsigned short* __restrict__ B,
    float* __restrict__ C, int Nt) {
  __shared__ unsigned short lds[3 * 24576];  // 144 KB
  const int tid = threadIdx.x;
  const int w = tid >> 6, l = tid & 63;
  const int wm = w >> 1, wn = w & 1;

  // XCD-pinned mapping: XCD x owns bn-stripe [x*16, x*16+16) (2 MB B,
  // L2-resident). Within XCD: 4bm x 16bn supertiles walked bm-fastest.
  const int bid = blockIdx.x;
  const int xcd = bid & 7;
  const int idx = bid >> 3;              // 0..255 per XCD
  const int st = idx >> 6;               // supertile row group 0..3
  const int bm = st * 4 + (idx & 3);     // 0..15
  const int bn = xcd * 16 + ((idx >> 2) & 15);  // 0..127

  const unsigned short* Ab = A + (size_t)bm * 256 * KP;
  const unsigned short* Bb = B + (size_t)bn * 128 * KP;

  f32x4 acc[4][4] = {};

  STAGE(0, 0);
  STAGE(1, 1);
  VMW(6);
  BAR();

  STAGE(2, 2); COMPUTE(0); VMW(6); BAR();  // t=0
  STAGE(3, 0); COMPUTE(1); VMW(6); BAR();  // t=1
  STAGE(4, 1); COMPUTE(2); VMW(6); BAR();  // t=2
  STAGE(5, 2); COMPUTE(0); VMW(6); BAR();  // t=3
  STAGE(6, 0); COMPUTE(1); VMW(6); BAR();  // t=4
  STAGE(7, 1); COMPUTE(2); VMW(6); BAR();  // t=5
  COMPUTE(0); VMW(0); BAR();               // t=6 (drain tile 7)
  COMPUTE(1);                              // t=7

  const int rb = bm * 256 + wm * 64 + (l >> 4) * 4;
  const int cb = bn * 128 + wn * 64 + (l & 15);
#pragma unroll
  for (int i2 = 0; i2 < 4; ++i2)
#pragma unroll
    for (int j2 = 0; j2 < 4; ++j2)
#pragma unroll
      for (int r = 0; r < 4; ++r)
        C[(size_t)(rb + i2 * 16 + r) * Nt + cb + j2 * 16] = acc[i2][j2][r];
}

extern "C" void kernel_launch(void* const* d_in, const int* in_sizes, int n_in,
                              void* d_out, int out_size, void* d_ws, size_t ws_size,
                              hipStream_t stream) {
  const float* x = (const float*)d_in[0];    // [n, 512]
  const float* cen = (const float*)d_in[1];  // [64, 256, 8]
  const int* tgt = (const int*)d_in[2];      // [m, 64]
  float* out = (float*)d_out;                // [n, m]
  const int n = in_sizes[0] / D_FULL;        // 4096
  const int m = in_sizes[2] / M_SUB;         // 16384

  unsigned short* Ap = (unsigned short*)d_ws;  // [n, 512] f16
  unsigned short* Bp = Ap + (size_t)n * KP;    // [m, 512] f16

  encode_kernel<<<dim3(M_SUB, n / 1024), 256, 0, stream>>>(x, cen, Ap);
  decode_tgt<<<dim3((m * M_SUB) / 256), 256, 0, stream>>>(tgt, cen, Bp);
  gemm_nt<<<dim3((n / 256) * (m / 128)), 512, 0, stream>>>(Ap, Bp, out, m);
}